// Round 5
// baseline (9090.770 us; speedup 1.0000x reference)
//
#include <hip/hip_runtime.h>
#include <hip/hip_bf16.h>
#include <math.h>

// Problem constants (match reference)
#define DT_     0.1f
#define TAU_M_  10.0f
#define TAU_S_  5.0f
#define NP_     8      // P populations
#define NN_     2048   // N neurons
#define NE_     16     // E edges
#define NB_     4      // B batch
#define NT_     128    // T steps
#define NEDGE_  17     // 16 recurrent + 1 input projection

// Fused-step geometry: block = (edge, j-tile); full K inside block.
#define JT_     16     // j tiles
#define JW_     128    // cols per tile
#define ST_     16     // i-strips per block
#define RS_     128    // rows per strip (ST_*RS_ == NN_)

typedef __attribute__((ext_vector_type(8))) _Float16 half8;
typedef __attribute__((ext_vector_type(8))) float    float8;

template <typename T> struct V8;
template <> struct V8<float>    { typedef float8 type; };
template <> struct V8<_Float16> { typedef half8  type; };

__device__ __forceinline__ float sigmoidf_(float x) {
  return 1.0f / (1.0f + expf(-x));
}

// One Euler v-step for (p,b,n): v_t = v_{t-1} + DT*f(v_{t-1}, s_t).
// MUST be the single definition used by all callers so redundant
// recomputation is bitwise identical everywhere.
__device__ __forceinline__ float vstep_(
    int p, int b, int n,
    const float* __restrict__ vA, const float* __restrict__ sA,
    const float* __restrict__ siA, const int* __restrict__ tgt,
    float* __restrict__ dv_out) {
  float vv = vA[((size_t)p * NB_ + b) * NN_ + n];
  float S = 0.0f;
#pragma unroll
  for (int e = 0; e < NE_; ++e)
    if (tgt[e] == p) S += sA[((size_t)e * NB_ + b) * NN_ + n];
  if (p == 0) S += siA[b * NN_ + n];
  float I  = S * (1.0f - vv);                      // E_REV=1, G_MAX=1
  float dv = (-vv - S * vv + I) * (1.0f / TAU_M_);
  *dv_out = dv;
  return vv + DT_ * dv;
}

// Convert fp32 weights (W then W_in, logical [17][N][N]) to fp16 in workspace.
__global__ __launch_bounds__(256) void k_convert(
    const float* __restrict__ W, const float* __restrict__ W_in,
    _Float16* __restrict__ Wh) {
  size_t idx = ((size_t)blockIdx.x * 256 + threadIdx.x) * 8;
  const size_t lim = (size_t)NE_ * NN_ * NN_;
  const float* src = (idx < lim) ? (W + idx) : (W_in + (idx - lim));
  float4 a = *(const float4*)src;
  float4 b = *(const float4*)(src + 4);
  half8 h;
  h[0] = (_Float16)a.x; h[1] = (_Float16)a.y; h[2] = (_Float16)a.z; h[3] = (_Float16)a.w;
  h[4] = (_Float16)b.x; h[5] = (_Float16)b.y; h[6] = (_Float16)b.z; h[7] = (_Float16)b.w;
  *(half8*)(Wh + idx) = h;
}

__global__ __launch_bounds__(256) void k_init(
    const float* __restrict__ v0, const float* __restrict__ s0,
    const float* __restrict__ s_in0,
    float* __restrict__ v, float* __restrict__ s, float* __restrict__ s_in,
    float* __restrict__ errpart) {
  int idx = blockIdx.x * 256 + threadIdx.x;
  if (idx < NE_ * NB_ * NN_) s[idx] = s0[idx];
  if (idx < NP_ * NB_ * NN_) v[idx] = v0[idx];
  if (idx < NB_ * NN_) s_in[idx] = s_in0[idx];
  if (idx < 256) errpart[idx] = 0.0f;
}

// Fused step kernel. Block (e, jt).
//  Phase P: compute pre = sigma(v_t)[src[e]] for ALL i into LDS (redundant,
//           deterministic); e==16 uses the analytic input rate.
//  Phase W: e<8 blocks are writers for population p=e over their j-range:
//           store v_t, out[t-1], err partial.
//  Main:    full-K matmul for this block's 128 columns (16 i-strips).
//  Reduce:  LDS strip reduction (fp16 partials, fp32 accumulate).
//  Phase S: synapse update s_{t+1} (or s_in_{t+1}) for this block's columns.
template <typename WT>
__global__ __launch_bounds__(256) void k_step(
    const WT* __restrict__ Wall, const WT* __restrict__ Win,
    const float* __restrict__ t_seq, const int* __restrict__ src,
    const int* __restrict__ tgt,
    const float* __restrict__ vA, float* __restrict__ vB,
    const float* __restrict__ sA, float* __restrict__ sB,
    const float* __restrict__ siA, float* __restrict__ siB,
    float* __restrict__ errpart, float* __restrict__ out, int t) {
  const int e   = blockIdx.x;   // 0..16
  const int jt  = blockIdx.y;   // 0..15
  const int tid = threadIdx.x;  // 0..255

  __shared__ float    preT[NN_][NB_];       // 32 KB, pre[i][b]
  __shared__ _Float16 redh[ST_][16][33];    // ~17 KB strip partials (padded)
  __shared__ float    shw[4];

  float esum = 0.0f;

  // ---- Phase P ----
  if (e == 16) {
    for (int k = tid; k < NB_ * NN_; k += 256) {
      int b = k >> 11, i = k & (NN_ - 1);
      float tt = t_seq[b * NT_ + t];
      float ph = (float)i * (6.2831853071795864f / (float)NN_);
      preT[i][b] = 0.5f * (1.0f + sinf(0.062831853071795864f * tt + ph));
    }
  } else {
    const int p = src[e];
    if (t == 0) {
      for (int k = tid; k < NB_ * NN_; k += 256) {
        int b = k >> 11, i = k & (NN_ - 1);
        preT[i][b] = sigmoidf_(vA[((size_t)p * NB_ + b) * NN_ + i]);
      }
    } else {
      for (int k = tid; k < NB_ * NN_; k += 256) {
        int b = k >> 11, i = k & (NN_ - 1);
        float dv;
        float vn = vstep_(p, b, i, vA, sA, siA, tgt, &dv);
        preT[i][b] = sigmoidf_(vn);
      }
    }
  }

  // ---- Phase W: writer duty ----
  if (e < NP_ && t > 0) {
    for (int k = tid; k < NB_ * JW_; k += 256) {
      int b = k >> 7, n = jt * JW_ + (k & (JW_ - 1));
      float dv;
      float vn = vstep_(e, b, n, vA, sA, siA, tgt, &dv);
      vB[((size_t)e * NB_ + b) * NN_ + n] = vn;
      float rr = sigmoidf_(vn);
      __builtin_nontemporal_store(
          rr, out + (((size_t)b * NT_ + (t - 1)) * NP_ + e) * NN_ + n);
      esum += fabsf(dv);
    }
  }
  __syncthreads();

  // ---- Main: full-K matmul for 128 cols ----
  const WT* Wp = (e == 16) ? Win : (Wall + (size_t)e * NN_ * NN_);
  const int jc = tid & 15;      // col-group of 8
  const int st = tid >> 4;      // i-strip
  const int j0 = jt * JW_ + jc * 8;

  float acc[NB_][8] = {};
  typedef typename V8<WT>::type vec8;
  const WT* wptr = Wp + (size_t)(st * RS_) * NN_ + j0;
  const float* pp = &preT[st * RS_][0];
#pragma unroll 4
  for (int r = 0; r < RS_; ++r) {
    vec8 w = *(const vec8*)wptr;
    wptr += NN_;
    float4 pv = *(const float4*)(pp + r * NB_);
#pragma unroll
    for (int k = 0; k < 8; ++k) {
      float wk = (float)w[k];
      acc[0][k] += pv.x * wk;
      acc[1][k] += pv.y * wk;
      acc[2][k] += pv.z * wk;
      acc[3][k] += pv.w * wk;
    }
  }

  // ---- Strip reduce ----
#pragma unroll
  for (int b = 0; b < NB_; ++b)
#pragma unroll
    for (int k = 0; k < 8; ++k)
      redh[st][jc][b * 8 + k] = (_Float16)acc[b][k];
  __syncthreads();

  // ---- Phase S: each thread finalizes 2 output slots ----
#pragma unroll
  for (int q = 0; q < 2; ++q) {
    int slot = tid * 2 + q;       // 0..511
    int sjc  = slot >> 5;         // 0..15
    int m    = slot & 31;         // b*8+k
    float d = 0.0f;
#pragma unroll
    for (int s2 = 0; s2 < ST_; ++s2) d += (float)redh[s2][sjc][m];
    int b = m >> 3, k = m & 7;
    int n = jt * JW_ + sjc * 8 + k;
    if (e < NE_) {
      float sv = sA[((size_t)e * NB_ + b) * NN_ + n];
      sB[((size_t)e * NB_ + b) * NN_ + n] =
          sv + DT_ * (d - sv * (1.0f / TAU_S_));
    } else {
      float sv = siA[b * NN_ + n];
      siB[b * NN_ + n] = sv + DT_ * (d - sv * (1.0f / TAU_S_));
    }
  }

  // ---- err partial (writer blocks only; block-uniform branch) ----
  if (e < NP_ && t > 0) {
    float es = esum;
#pragma unroll
    for (int off = 32; off > 0; off >>= 1)
      es += __shfl_down(es, off, 64);
    if ((tid & 63) == 0) shw[tid >> 6] = es;
    __syncthreads();
    if (tid == 0)
      errpart[e * JT_ + jt] += shw[0] + shw[1] + shw[2] + shw[3];
  }
}

// Final v-update for step T-1: out[T-1] + err partials (slots 128..255).
__global__ __launch_bounds__(256) void k_last(
    const int* __restrict__ tgt,
    const float* __restrict__ vA, const float* __restrict__ sA,
    const float* __restrict__ siA,
    float* __restrict__ errpart, float* __restrict__ out) {
  const int p = blockIdx.x, jt = blockIdx.y, tid = threadIdx.x;
  __shared__ float shw[4];
  float esum = 0.0f;
  for (int k = tid; k < NB_ * JW_; k += 256) {
    int b = k >> 7, n = jt * JW_ + (k & (JW_ - 1));
    float dv;
    float vn = vstep_(p, b, n, vA, sA, siA, tgt, &dv);
    float rr = sigmoidf_(vn);
    __builtin_nontemporal_store(
        rr, out + (((size_t)b * NT_ + (NT_ - 1)) * NP_ + p) * NN_ + n);
    esum += fabsf(dv);
  }
#pragma unroll
  for (int off = 32; off > 0; off >>= 1)
    esum += __shfl_down(esum, off, 64);
  if ((tid & 63) == 0) shw[tid >> 6] = esum;
  __syncthreads();
  if (tid == 0)
    errpart[NP_ * JT_ + p * JT_ + jt] = shw[0] + shw[1] + shw[2] + shw[3];
}

__global__ void k_err(const float* __restrict__ errpart,
                      float* __restrict__ out_err) {
  if (threadIdx.x == 0) {
    float s = 0.0f;
    for (int i = 0; i < 256; ++i) s += errpart[i];
    *out_err = s * (DT_ / (float)(NP_ * NB_ * NN_));
  }
}

extern "C" void kernel_launch(void* const* d_in, const int* in_sizes, int n_in,
                              void* d_out, int out_size, void* d_ws, size_t ws_size,
                              hipStream_t stream) {
  const float* t_seq = (const float*)d_in[0];   // [B,T]
  const float* W     = (const float*)d_in[1];   // [E,N,N]
  const float* W_in  = (const float*)d_in[2];   // [N,N]
  const float* v0    = (const float*)d_in[3];   // [P,B,N]
  const float* s0    = (const float*)d_in[4];   // [E,B,N]
  const float* s_in0 = (const float*)d_in[5];   // [B,N]
  const int*   src   = (const int*)d_in[6];     // [E]
  const int*   tgt   = (const int*)d_in[7];     // [E]
  float* out = (float*)d_out;                   // [B,T,P,N] + err

  const size_t WH_ELEMS = (size_t)NEDGE_ * NN_ * NN_;  // 71,303,168 halves
  const size_t SB = (size_t)NE_ * NB_ * NN_;           // 131072
  const size_t VB = (size_t)NP_ * NB_ * NN_;           // 65536
  const size_t IB = (size_t)NB_ * NN_;                 // 8192
  const size_t STATE_F = 2 * SB + 2 * VB + 2 * IB + 256;
  const size_t NEED_H = WH_ELEMS * sizeof(_Float16) + STATE_F * sizeof(float);
  const bool useHalf = ws_size >= NEED_H;

  _Float16* Wh = useHalf ? (_Float16*)d_ws : nullptr;
  float* fbase = useHalf ? (float*)(Wh + WH_ELEMS) : (float*)d_ws;
  float* sbuf0 = fbase;
  float* sbuf1 = sbuf0 + SB;
  float* vbuf0 = sbuf1 + SB;
  float* vbuf1 = vbuf0 + VB;
  float* ibuf0 = vbuf1 + VB;
  float* ibuf1 = ibuf0 + IB;
  float* errpart = ibuf1 + IB;

  float* sbuf[2] = {sbuf0, sbuf1};
  float* vbuf[2] = {vbuf0, vbuf1};
  float* ibuf[2] = {ibuf0, ibuf1};

  if (useHalf) {
    hipLaunchKernelGGL(k_convert, dim3((unsigned)(WH_ELEMS / (8 * 256))),
                       dim3(256), 0, stream, W, W_in, Wh);
  }
  hipLaunchKernelGGL(k_init, dim3(512), dim3(256), 0, stream,
                     v0, s0, s_in0, vbuf0, sbuf0, ibuf0, errpart);

  for (int t = 0; t < NT_; ++t) {
    const float* vA = vbuf[(t == 0) ? 0 : ((t - 1) & 1)];
    float*       vBp = vbuf[t & 1];
    const float* sA = sbuf[t & 1];
    float*       sBp = sbuf[(t + 1) & 1];
    const float* iA = ibuf[t & 1];
    float*       iBp = ibuf[(t + 1) & 1];
    if (useHalf) {
      hipLaunchKernelGGL((k_step<_Float16>), dim3(NEDGE_, JT_), dim3(256), 0,
                         stream, Wh, Wh + (size_t)NE_ * NN_ * NN_, t_seq, src,
                         tgt, vA, vBp, sA, sBp, iA, iBp, errpart, out, t);
    } else {
      hipLaunchKernelGGL((k_step<float>), dim3(NEDGE_, JT_), dim3(256), 0,
                         stream, W, W_in, t_seq, src,
                         tgt, vA, vBp, sA, sBp, iA, iBp, errpart, out, t);
    }
  }

  // v_{T-1} lives in vbuf[(T-1)&1] = vbuf[1]; s_T in sbuf[T&1] = sbuf[0].
  hipLaunchKernelGGL(k_last, dim3(NP_, JT_), dim3(256), 0, stream,
                     tgt, vbuf[1], sbuf[0], ibuf[0], errpart, out);
  hipLaunchKernelGGL(k_err, dim3(1), dim3(64), 0, stream,
                     errpart, out + (size_t)NB_ * NT_ * NP_ * NN_);
}

// Round 6
// 5034.181 us; speedup vs baseline: 1.8058x; 1.8058x over previous
//
#include <hip/hip_runtime.h>
#include <hip/hip_bf16.h>
#include <math.h>

// Problem constants (match reference)
#define DT_     0.1f
#define TAU_M_  10.0f
#define TAU_S_  5.0f
#define NP_     8      // P populations
#define NN_     2048   // N neurons
#define NE_     16     // E edges
#define NB_     4      // B batch
#define NT_     128    // T steps
#define NEDGE_  17     // 16 recurrent + 1 input projection

// Step-A geometry: block = (edge, j-tile). Full K per block,
// split across ST_ strips inside the block, LDS reduce.
#define JT_     16     // j tiles
#define JW_     128    // cols per tile
#define ST_     16     // i-strips per block
#define RS_     128    // rows per strip (ST_*RS_ == NN_)

typedef __attribute__((ext_vector_type(8))) _Float16 half8;
typedef __attribute__((ext_vector_type(8))) float    float8;

template <typename T> struct V8;
template <> struct V8<float>    { typedef float8 type; };
template <> struct V8<_Float16> { typedef half8  type; };

__device__ __forceinline__ float sigmoidf_(float x) {
  return 1.0f / (1.0f + expf(-x));
}

// Convert fp32 weights (W then W_in, logical [17][N][N]) to fp16 in workspace.
__global__ __launch_bounds__(256) void k_convert(
    const float* __restrict__ W, const float* __restrict__ W_in,
    _Float16* __restrict__ Wh) {
  size_t idx = ((size_t)blockIdx.x * 256 + threadIdx.x) * 8;
  const size_t lim = (size_t)NE_ * NN_ * NN_;
  const float* src = (idx < lim) ? (W + idx) : (W_in + (idx - lim));
  float4 a = *(const float4*)src;
  float4 b = *(const float4*)(src + 4);
  half8 h;
  h[0] = (_Float16)a.x; h[1] = (_Float16)a.y; h[2] = (_Float16)a.z; h[3] = (_Float16)a.w;
  h[4] = (_Float16)b.x; h[5] = (_Float16)b.y; h[6] = (_Float16)b.z; h[7] = (_Float16)b.w;
  *(half8*)(Wh + idx) = h;
}

__global__ __launch_bounds__(256) void k_init(
    const float* __restrict__ v0, const float* __restrict__ s0,
    const float* __restrict__ s_in0,
    float* __restrict__ v, float* __restrict__ s, float* __restrict__ s_in,
    float* __restrict__ rates, float* __restrict__ errpart) {
  int idx = blockIdx.x * 256 + threadIdx.x;
  if (idx < NE_ * NB_ * NN_) s[idx] = s0[idx];
  if (idx < NP_ * NB_ * NN_) {
    float vv = v0[idx];
    v[idx] = vv;
    rates[idx] = sigmoidf_(vv);   // rates_0 = sigma(v_0)
  }
  if (idx < NB_ * NN_) s_in[idx] = s_in0[idx];
  if (idx < 256) errpart[idx] = 0.0f;
}

// Kernel A2: full-K matmul + in-place synapse update; no global partials.
// Block (e, jt): stages rates[src[e]] (or analytic input rate) to LDS,
// computes drive for its 128 columns (16 strips x 128 rows), LDS-reduces,
// writes s_{t+1} in place.
template <typename WT>
__global__ __launch_bounds__(256) void k_stepA2(
    const WT* __restrict__ Wall, const WT* __restrict__ Win,
    const float* __restrict__ rates, const float* __restrict__ t_seq,
    const int* __restrict__ src,
    float* __restrict__ s, float* __restrict__ s_in, int t) {
  const int e   = blockIdx.x;   // 0..16 (16 == input projection)
  const int jt  = blockIdx.y;   // 0..15
  const int tid = threadIdx.x;  // 0..255

  __shared__ float preT[NB_][NN_];        // 32 KB, [b][i]
  __shared__ float redf[ST_][16][33];     // 33.8 KB strip partials (padded)

  // ---- Stage pre-activity (read-only; no recompute) ----
  if (e == 16) {
    for (int k = tid; k < NB_ * NN_; k += 256) {
      int b = k >> 11, i = k & (NN_ - 1);
      float tt = t_seq[b * NT_ + t];
      float ph = (float)i * (6.2831853071795864f / (float)NN_);
      preT[b][i] = 0.5f * (1.0f + sinf(0.062831853071795864f * tt + ph));
    }
  } else {
    const int sp = src[e];
    const float* rp = rates + (size_t)sp * NB_ * NN_;
    for (int k = tid; k < NB_ * NN_; k += 256) {
      int b = k >> 11, i = k & (NN_ - 1);
      preT[b][i] = rp[b * NN_ + i];
    }
  }
  __syncthreads();

  // ---- Main: strip matmul ----
  const WT* Wp = (e == 16) ? Win : (Wall + (size_t)e * NN_ * NN_);
  const int jc = tid & 15;      // col-group of 8
  const int st = tid >> 4;      // i-strip
  const int j0 = jt * JW_ + jc * 8;
  const int i0 = st * RS_;

  float acc[NB_][8] = {};
  typedef typename V8<WT>::type vec8;
  const WT* wptr = Wp + (size_t)i0 * NN_ + j0;
#pragma unroll 8
  for (int r = 0; r < RS_; ++r) {
    vec8 w = *(const vec8*)wptr;
    wptr += NN_;
    float p0 = preT[0][i0 + r];
    float p1 = preT[1][i0 + r];
    float p2 = preT[2][i0 + r];
    float p3 = preT[3][i0 + r];
#pragma unroll
    for (int k = 0; k < 8; ++k) {
      float wk = (float)w[k];
      acc[0][k] += p0 * wk;
      acc[1][k] += p1 * wk;
      acc[2][k] += p2 * wk;
      acc[3][k] += p3 * wk;
    }
  }

  // ---- Strip reduce (fp32 in LDS) ----
#pragma unroll
  for (int b = 0; b < NB_; ++b)
#pragma unroll
    for (int k = 0; k < 8; ++k)
      redf[st][jc][b * 8 + k] = acc[b][k];
  __syncthreads();

  // ---- Phase S: finalize 2 slots/thread, in-place s update ----
#pragma unroll
  for (int q = 0; q < 2; ++q) {
    int slot = tid * 2 + q;       // 0..511
    int sjc  = slot >> 5;         // 0..15
    int m    = slot & 31;         // b*8+k
    float d = 0.0f;
#pragma unroll
    for (int s2 = 0; s2 < ST_; ++s2) d += redf[s2][sjc][m];
    int b = m >> 3, k = m & 7;
    int n = jt * JW_ + sjc * 8 + k;
    if (e < NE_) {
      float* sp2 = s + ((size_t)e * NB_ + b) * NN_ + n;
      float sv = *sp2;
      *sp2 = sv + DT_ * (d - sv * (1.0f / TAU_S_));
    } else {
      float* sp2 = s_in + b * NN_ + n;
      float sv = *sp2;
      *sp2 = sv + DT_ * (d - sv * (1.0f / TAU_S_));
    }
  }
}

// Kernel B: segment-sum over edges, membrane update, rates + outputs + err.
__global__ __launch_bounds__(256) void k_stepB(
    const float* __restrict__ s, const float* __restrict__ s_in,
    const int* __restrict__ tgt,
    float* __restrict__ v, float* __restrict__ rates,
    float* __restrict__ errpart, float* __restrict__ out, int step) {
  const int idx = blockIdx.x * 256 + threadIdx.x;
  const int p = idx >> 13;
  const int b = (idx >> 11) & (NB_ - 1);
  const int n = idx & (NN_ - 1);

  int tg[NE_];
#pragma unroll
  for (int e = 0; e < NE_; ++e) tg[e] = tgt[e];

  float S = 0.0f;
#pragma unroll
  for (int e = 0; e < NE_; ++e) {
    if (tg[e] == p) S += s[((size_t)e * NB_ + b) * NN_ + n];
  }
  if (p == 0) S += s_in[b * NN_ + n];

  float* vp = v + ((size_t)p * NB_ + b) * NN_ + n;
  float vv = *vp;
  float I  = S * (1.0f - vv);      // E_REV=1, G_MAX=1
  float dv = (-vv - S * vv + I) * (1.0f / TAU_M_);
  float vn = vv + DT_ * dv;
  *vp = vn;
  float rr = sigmoidf_(vn);
  rates[((size_t)p * NB_ + b) * NN_ + n] = rr;
  __builtin_nontemporal_store(rr, out + (((size_t)b * NT_ + step) * NP_ + p) * NN_ + n);

  // deterministic per-block err partial (raw |dv| sums; scaled in k_err)
  __shared__ float red[256];
  red[threadIdx.x] = fabsf(dv);
  __syncthreads();
  for (int w = 128; w > 0; w >>= 1) {
    if (threadIdx.x < w) red[threadIdx.x] += red[threadIdx.x + w];
    __syncthreads();
  }
  if (threadIdx.x == 0) {
    errpart[blockIdx.x] += red[0];
  }
}

__global__ void k_err(const float* __restrict__ errpart,
                      float* __restrict__ out_err) {
  if (threadIdx.x == 0) {
    float sum = 0.0f;
    for (int i = 0; i < 256; ++i) sum += errpart[i];
    *out_err = sum * (DT_ / (float)(NP_ * NB_ * NN_));
  }
}

extern "C" void kernel_launch(void* const* d_in, const int* in_sizes, int n_in,
                              void* d_out, int out_size, void* d_ws, size_t ws_size,
                              hipStream_t stream) {
  const float* t_seq = (const float*)d_in[0];   // [B,T]
  const float* W     = (const float*)d_in[1];   // [E,N,N]
  const float* W_in  = (const float*)d_in[2];   // [N,N]
  const float* v0    = (const float*)d_in[3];   // [P,B,N]
  const float* s0    = (const float*)d_in[4];   // [E,B,N]
  const float* s_in0 = (const float*)d_in[5];   // [B,N]
  const int*   src   = (const int*)d_in[6];     // [E]
  const int*   tgt   = (const int*)d_in[7];     // [E]
  float* out = (float*)d_out;                   // [B,T,P,N] + err

  const size_t WH_ELEMS = (size_t)NEDGE_ * NN_ * NN_;  // 71,303,168 halves
  const size_t SB = (size_t)NE_ * NB_ * NN_;           // 131072
  const size_t VB = (size_t)NP_ * NB_ * NN_;           // 65536
  const size_t IB = (size_t)NB_ * NN_;                 // 8192
  const size_t STATE_F = SB + VB + IB + VB + 256;      // s, v, s_in, rates, errpart
  const size_t NEED_H = WH_ELEMS * sizeof(_Float16) + STATE_F * sizeof(float);
  const bool useHalf = ws_size >= NEED_H;

  _Float16* Wh = useHalf ? (_Float16*)d_ws : nullptr;
  float* fbase = useHalf ? (float*)(Wh + WH_ELEMS) : (float*)d_ws;
  float* s       = fbase;
  float* v       = s + SB;
  float* s_in    = v + VB;
  float* rates   = s_in + IB;
  float* errpart = rates + VB;

  if (useHalf) {
    hipLaunchKernelGGL(k_convert, dim3((unsigned)(WH_ELEMS / (8 * 256))),
                       dim3(256), 0, stream, W, W_in, Wh);
  }
  hipLaunchKernelGGL(k_init, dim3(512), dim3(256), 0, stream,
                     v0, s0, s_in0, v, s, s_in, rates, errpart);

  for (int t = 0; t < NT_; ++t) {
    if (useHalf) {
      hipLaunchKernelGGL((k_stepA2<_Float16>), dim3(NEDGE_, JT_), dim3(256), 0,
                         stream, Wh, Wh + (size_t)NE_ * NN_ * NN_,
                         rates, t_seq, src, s, s_in, t);
    } else {
      hipLaunchKernelGGL((k_stepA2<float>), dim3(NEDGE_, JT_), dim3(256), 0,
                         stream, W, W_in, rates, t_seq, src, s, s_in, t);
    }
    hipLaunchKernelGGL(k_stepB, dim3(256), dim3(256), 0, stream,
                       s, s_in, tgt, v, rates, errpart, out, t);
  }

  hipLaunchKernelGGL(k_err, dim3(1), dim3(64), 0, stream,
                     errpart, out + (size_t)NB_ * NT_ * NP_ * NN_);
}

// Round 7
// 4106.623 us; speedup vs baseline: 2.2137x; 1.2259x over previous
//
#include <hip/hip_runtime.h>
#include <hip/hip_bf16.h>
#include <math.h>

// Problem constants (match reference)
#define DT_     0.1f
#define TAU_M_  10.0f
#define TAU_S_  5.0f
#define NP_     8      // P populations
#define NN_     2048   // N neurons
#define NE_     16     // E edges
#define NB_     4      // B batch
#define NT_     128    // T steps

#define CH_     16     // split-K chunks over i (272 blocks, all co-resident)
#define IL_     128    // rows per chunk (CH_*IL_ == NN_)
#define NEDGE_  17     // 16 recurrent + 1 input projection

typedef __attribute__((ext_vector_type(8))) _Float16 half8;
typedef __attribute__((ext_vector_type(8))) float    float8;

template <typename T> struct V8;
template <> struct V8<float>    { typedef float8 type; };
template <> struct V8<_Float16> { typedef half8  type; };

__device__ __forceinline__ float sigmoidf_(float x) {
  return 1.0f / (1.0f + expf(-x));
}

// Convert fp32 weights (W then W_in, logical [17][N][N]) to fp16 in workspace.
__global__ __launch_bounds__(256) void k_convert(
    const float* __restrict__ W, const float* __restrict__ W_in,
    _Float16* __restrict__ Wh) {
  size_t idx = ((size_t)blockIdx.x * 256 + threadIdx.x) * 8;
  const size_t lim = (size_t)NE_ * NN_ * NN_;
  const float* src = (idx < lim) ? (W + idx) : (W_in + (idx - lim));
  float4 a = *(const float4*)src;
  float4 b = *(const float4*)(src + 4);
  half8 h;
  h[0] = (_Float16)a.x; h[1] = (_Float16)a.y; h[2] = (_Float16)a.z; h[3] = (_Float16)a.w;
  h[4] = (_Float16)b.x; h[5] = (_Float16)b.y; h[6] = (_Float16)b.z; h[7] = (_Float16)b.w;
  *(half8*)(Wh + idx) = h;
}

__global__ __launch_bounds__(256) void k_init(
    const float* __restrict__ v0, const float* __restrict__ s0,
    const float* __restrict__ s_in0,
    float* __restrict__ v, float* __restrict__ s, float* __restrict__ s_in,
    float* __restrict__ rates, float* __restrict__ errpart) {
  int idx = blockIdx.x * 256 + threadIdx.x;
  if (idx < NE_ * NB_ * NN_) s[idx] = s0[idx];
  if (idx < NP_ * NB_ * NN_) {
    float vv = v0[idx];
    v[idx] = vv;
    rates[idx] = sigmoidf_(vv);
  }
  if (idx < NB_ * NN_) s_in[idx] = s_in0[idx];
  if (idx < 256) errpart[idx] = 0.0f;
}

// Kernel A: split-K matmul (exact R2 structure; only the partial store is fp16).
// part[ch][e][b][j] = sum_{i in chunk} pre[e,b,i]*W[e,i,j]
template <typename WT>
__global__ __launch_bounds__(256) void k_stepA(
    const WT* __restrict__ Wall, const WT* __restrict__ Win,
    const float* __restrict__ rates, const float* __restrict__ t_seq,
    const int* __restrict__ src, _Float16* __restrict__ part, int step) {
  const int e   = blockIdx.x;   // 0..16 (16 == input projection)
  const int ch  = blockIdx.y;   // 0..CH_-1
  const int tid = threadIdx.x;  // 0..255

  __shared__ float pre[NB_][IL_];
  const int i0 = ch * IL_;

  for (int k = tid; k < NB_ * IL_; k += 256) {
    int b  = k >> 7;
    int il = k & (IL_ - 1);
    float val;
    if (e == 16) {
      float t = t_seq[b * NT_ + step];
      float phase = (float)(i0 + il) * (6.2831853071795864f / (float)NN_);
      val = 0.5f * (1.0f + sinf(0.062831853071795864f * t + phase));
    } else {
      val = rates[(src[e] * NB_ + b) * NN_ + (i0 + il)];
    }
    pre[b][il] = val;
  }
  __syncthreads();

  const WT* Wp = (e == 16) ? Win : (Wall + (size_t)e * NN_ * NN_);
  const int j = tid * 8;

  float acc[NB_][8] = {};
  typedef typename V8<WT>::type vec8;
#pragma unroll 4
  for (int il = 0; il < IL_; ++il) {
    vec8 w = *(const vec8*)(Wp + (size_t)(i0 + il) * NN_ + j);
    float wf[8];
#pragma unroll
    for (int k = 0; k < 8; ++k) wf[k] = (float)w[k];
#pragma unroll
    for (int b = 0; b < NB_; ++b) {
      float p = pre[b][il];
#pragma unroll
      for (int k = 0; k < 8; ++k) acc[b][k] += p * wf[k];
    }
  }

#pragma unroll
  for (int b = 0; b < NB_; ++b) {
    half8 o;
#pragma unroll
    for (int k = 0; k < 8; ++k) o[k] = (_Float16)acc[b][k];
    *(half8*)(part + (((size_t)ch * NEDGE_ + e) * NB_ + b) * NN_ + j) = o;
  }
}

// Fused kernel RB: vectorized partial reduce + s update (Phase R),
// then segment-sum + v update + outputs (Phase B) from LDS.
// Grid: 64 blocks = (b, n-tile of 128 cols). 256 threads.
__global__ __launch_bounds__(256) void k_stepRB(
    const _Float16* __restrict__ part, const int* __restrict__ tgt,
    float* __restrict__ v, float* __restrict__ s, float* __restrict__ s_in,
    float* __restrict__ rates, float* __restrict__ errpart,
    float* __restrict__ out, int step) {
  const int blk = blockIdx.x;          // 0..63
  const int b   = blk >> 4;            // 0..3
  const int n0  = (blk & 15) * 128;
  const int tid = threadIdx.x;

  __shared__ float sh_s[NEDGE_][128];  // 8.7 KB
  __shared__ float red[4];

  // ---- Phase R: 272 half8-groups (17 e x 16 col-octets) ----
  for (int g = tid; g < NEDGE_ * 16; g += 256) {
    int e  = g >> 4;
    int c8 = g & 15;
    int n  = n0 + c8 * 8;
    float acc[8] = {};
#pragma unroll
    for (int c = 0; c < CH_; ++c) {
      half8 pv = *(const half8*)(part + (((size_t)c * NEDGE_ + e) * NB_ + b) * NN_ + n);
#pragma unroll
      for (int k = 0; k < 8; ++k) acc[k] += (float)pv[k];
    }
    float* sp = (e == 16) ? (s_in + b * NN_ + n)
                          : (s + ((size_t)e * NB_ + b) * NN_ + n);
#pragma unroll
    for (int k = 0; k < 8; ++k) {
      float sv = sp[k];
      sv += DT_ * (acc[k] - sv * (1.0f / TAU_S_));
      sp[k] = sv;
      sh_s[e][c8 * 8 + k] = sv;
    }
  }
  __syncthreads();

  // ---- Phase B: p = tid>>5, 4 cols per thread (stride 32) ----
  int tg[NE_];
#pragma unroll
  for (int e = 0; e < NE_; ++e) tg[e] = tgt[e];

  const int p = tid >> 5;
  float errsum = 0.0f;
#pragma unroll
  for (int q = 0; q < 4; ++q) {
    int nc = (tid & 31) + q * 32;     // 0..127
    float S = 0.0f;
#pragma unroll
    for (int e = 0; e < NE_; ++e)
      if (tg[e] == p) S += sh_s[e][nc];
    if (p == 0) S += sh_s[16][nc];

    int n = n0 + nc;
    float* vp = v + ((size_t)p * NB_ + b) * NN_ + n;
    float vv = *vp;
    float I  = S * (1.0f - vv);      // E_REV=1, G_MAX=1
    float dv = (-vv - S * vv + I) * (1.0f / TAU_M_);
    float vn = vv + DT_ * dv;
    *vp = vn;
    errsum += fabsf(dv);
    float rr = sigmoidf_(vn);
    rates[((size_t)p * NB_ + b) * NN_ + n] = rr;
    __builtin_nontemporal_store(
        rr, out + (((size_t)b * NT_ + step) * NP_ + p) * NN_ + n);
  }

  // ---- deterministic per-block err partial (raw sums; scaled in k_err) ----
#pragma unroll
  for (int off = 32; off > 0; off >>= 1)
    errsum += __shfl_down(errsum, off, 64);
  if ((tid & 63) == 0) red[tid >> 6] = errsum;
  __syncthreads();
  if (tid == 0)
    errpart[blk] += red[0] + red[1] + red[2] + red[3];
}

__global__ void k_err(const float* __restrict__ errpart,
                      float* __restrict__ out_err) {
  if (threadIdx.x == 0) {
    float sum = 0.0f;
    for (int i = 0; i < 256; ++i) sum += errpart[i];
    *out_err = sum * (DT_ / (float)(NP_ * NB_ * NN_));
  }
}

extern "C" void kernel_launch(void* const* d_in, const int* in_sizes, int n_in,
                              void* d_out, int out_size, void* d_ws, size_t ws_size,
                              hipStream_t stream) {
  const float* t_seq = (const float*)d_in[0];   // [B,T]
  const float* W     = (const float*)d_in[1];   // [E,N,N]
  const float* W_in  = (const float*)d_in[2];   // [N,N]
  const float* v0    = (const float*)d_in[3];   // [P,B,N]
  const float* s0    = (const float*)d_in[4];   // [E,B,N]
  const float* s_in0 = (const float*)d_in[5];   // [B,N]
  const int*   src   = (const int*)d_in[6];     // [E]
  const int*   tgt   = (const int*)d_in[7];     // [E]
  float* out = (float*)d_out;                   // [B,T,P,N] + err

  const size_t WH_ELEMS = (size_t)NEDGE_ * NN_ * NN_;        // 71,303,168 halves
  const size_t PART_H   = (size_t)CH_ * NEDGE_ * NB_ * NN_;  // 2,228,224 halves
  const size_t STATE_F  = 131072 + 65536 + 8192 + 65536 + 256;
  const size_t NEED_H   = (WH_ELEMS + PART_H) * sizeof(_Float16) + STATE_F * sizeof(float);
  const bool useHalf = ws_size >= NEED_H;

  _Float16* Wh;
  _Float16* part;
  if (useHalf) {
    Wh   = (_Float16*)d_ws;
    part = Wh + WH_ELEMS;
  } else {
    Wh   = nullptr;
    part = (_Float16*)d_ws;
  }
  float* s       = (float*)(part + PART_H);
  float* v       = s + NE_ * NB_ * NN_;
  float* s_in    = v + NP_ * NB_ * NN_;
  float* rates   = s_in + NB_ * NN_;
  float* errpart = rates + NP_ * NB_ * NN_;

  if (useHalf) {
    hipLaunchKernelGGL(k_convert, dim3((unsigned)(WH_ELEMS / (8 * 256))),
                       dim3(256), 0, stream, W, W_in, Wh);
  }
  hipLaunchKernelGGL(k_init, dim3(512), dim3(256), 0, stream,
                     v0, s0, s_in0, v, s, s_in, rates, errpart);

  for (int t = 0; t < NT_; ++t) {
    if (useHalf) {
      hipLaunchKernelGGL((k_stepA<_Float16>), dim3(NEDGE_, CH_), dim3(256), 0,
                         stream, Wh, Wh + (size_t)NE_ * NN_ * NN_,
                         rates, t_seq, src, part, t);
    } else {
      hipLaunchKernelGGL((k_stepA<float>), dim3(NEDGE_, CH_), dim3(256), 0,
                         stream, W, W_in, rates, t_seq, src, part, t);
    }
    hipLaunchKernelGGL(k_stepRB, dim3(64), dim3(256), 0, stream,
                       part, tgt, v, s, s_in, rates, errpart, out, t);
  }

  hipLaunchKernelGGL(k_err, dim3(1), dim3(64), 0, stream,
                     errpart, out + (size_t)NB_ * NT_ * NP_ * NN_);
}